// Round 6
// baseline (51.055 us; speedup 1.0000x reference)
//
#include <hip/hip_runtime.h>

namespace {

typedef short  bf16x8 __attribute__((ext_vector_type(8)));
typedef float  f32x4  __attribute__((ext_vector_type(4)));

constexpr int D = 1024;   // in_features
constexpr int O = 1024;   // out_features

// fp32 -> bf16 bits, round-to-nearest-even
__device__ __forceinline__ short f2bf(float f) {
    unsigned u = __builtin_bit_cast(unsigned, f);
    u += 0x7fffu + ((u >> 16) & 1u);
    return (short)(u >> 16);
}

__device__ __forceinline__ bf16x8 cvt8(const float4 a, const float4 b) {
    bf16x8 v;
    v[0] = f2bf(a.x); v[1] = f2bf(a.y); v[2] = f2bf(a.z); v[3] = f2bf(a.w);
    v[4] = f2bf(b.x); v[5] = f2bf(b.y); v[6] = f2bf(b.z); v[7] = f2bf(b.w);
    return v;
}

// Fused LoRA. 512 blocks x 256 threads (4 waves) -> 2 blocks/CU (two
// independent barrier domains per CU so staging stalls of one block hide
// under compute/streams of the other). Block owns 32 rows.
// Wave w: rt = w>>1 (16-row tile), kh = w&1 (K-half / N-half split).
// B-operands staged in LDS (bf16, converted in-flight from f32); inner
// loops are ds_read + MFMA only. pacc is aliased into bs (never co-live).
__global__ void __launch_bounds__(256) lora_mfma_k(
        const float* __restrict__ hs,     // [16384][1024] f32
        const float* __restrict__ alpha,  // [4][4]
        const float* __restrict__ dw,     // [64][1024] f32  (k*16+r major)
        const float* __restrict__ uw,     // [4][1024][16] f32
        float* __restrict__ out) {        // [16384][1024] f32
    // bs: phase-1 chunk [64][264] (33.8KB) / phase-2 chunk [256][72] (36.9KB)
    __shared__ __align__(16) short bs[18432];        // 36864 B
    __shared__ __align__(16) short lowb[2][16][72];  // 4608 B
    float* pacc = reinterpret_cast<float*>(bs);      // [2][16][64] f32, aliased

    const int t    = threadIdx.x;
    const int w    = t >> 6;
    const int lane = t & 63;
    const int rt   = w >> 1;            // row-tile 0..1
    const int kh   = w & 1;             // K-half / N-half
    const int fr   = lane & 15;
    const int kgi  = lane >> 4;         // 0..3
    const int kg   = kgi * 8;
    const int rowblk = blockIdx.x * 32;
    const int b      = rowblk >> 12;    // batch (32-row blocks never straddle)
    const int myrow  = rowblk + rt * 16 + fr;

    // ---------------- phase 1: low = hs @ dw^T (K split across wave pair) ----------------
    f32x4 acc[4];
#pragma unroll
    for (int nt = 0; nt < 4; ++nt) acc[nt] = (f32x4){0.f, 0.f, 0.f, 0.f};

#pragma unroll 1
    for (int c = 0; c < 4; ++c) {
        __syncthreads();   // previous chunk's bs reads complete
        // stage dw[0..64][c*256..+256] -> bs[kr][264], f32->bf16 in flight
#pragma unroll
        for (int i = 0; i < 8; ++i) {
            const int e  = i * 256 + t;     // 0..2047
            const int kr = e >> 5;          // 0..63
            const int cc = e & 31;          // 16B chunk within 256-col row
            const float* sp = dw + (size_t)kr * D + c * 256 + cc * 8;
            const float4 s0 = *reinterpret_cast<const float4*>(sp);
            const float4 s1 = *reinterpret_cast<const float4*>(sp + 4);
            *reinterpret_cast<bf16x8*>(&bs[kr * 264 + cc * 8]) = cvt8(s0, s1);
        }
        __syncthreads();

        const float* ap = hs + (size_t)myrow * D + c * 256 + kh * 128 + kg;
#pragma unroll
        for (int ks = 0; ks < 4; ++ks) {
            const float4 a0 = *reinterpret_cast<const float4*>(ap + ks * 32);
            const float4 a1 = *reinterpret_cast<const float4*>(ap + ks * 32 + 4);
            const bf16x8 av = cvt8(a0, a1);
#pragma unroll
            for (int nt = 0; nt < 4; ++nt) {
                const bf16x8 bv = *reinterpret_cast<const bf16x8*>(
                    &bs[(nt * 16 + fr) * 264 + kh * 128 + ks * 32 + kg]);
                acc[nt] = __builtin_amdgcn_mfma_f32_16x16x32_bf16(av, bv, acc[nt], 0, 0, 0);
            }
        }
    }

    // combine split-K partials (pacc aliases bs; barriers separate uses);
    // scale by alpha*4; bf16 low tile in LDS
    __syncthreads();   // all bs reads of last chunk complete
    if (kh) {
#pragma unroll
        for (int nt = 0; nt < 4; ++nt)
#pragma unroll
            for (int j = 0; j < 4; ++j)
                pacc[(rt * 16 + nt * 4 + j) * 64 + lane] = acc[nt][j];
    }
    __syncthreads();
    if (!kh) {
#pragma unroll
        for (int nt = 0; nt < 4; ++nt) {
            const float sc = alpha[b * 4 + nt] * 4.0f;   // NETWORK_ALPHA/RANK = 4
#pragma unroll
            for (int j = 0; j < 4; ++j) {
                const float v = (acc[nt][j] + pacc[(rt * 16 + nt * 4 + j) * 64 + lane]) * sc;
                lowb[rt][kgi * 4 + j][nt * 16 + fr] = f2bf(v);
            }
        }
    }
    __syncthreads();   // pacc reads done (bs free), lowb visible

    // ---------------- phase 2: out = low @ up^T (N split across wave pair) ----------------
    const bf16x8 pa0 = *reinterpret_cast<const bf16x8*>(&lowb[rt][fr][kg]);
    const bf16x8 pa1 = *reinterpret_cast<const bf16x8*>(&lowb[rt][fr][32 + kg]);

    float* op = out + (size_t)(rowblk + rt * 16 + kgi * 4) * O;

#pragma unroll 1
    for (int oc = 0; oc < 4; ++oc) {
        // stage up chunk: bs[o][72] = bf16(uw[k][oc*256+o][r]), kr=k*16+r
#pragma unroll
        for (int i = 0; i < 8; ++i) {
            const int e  = i * 256 + t;     // 0..2047
            const int o  = e >> 3;          // 0..255 (row within chunk)
            const int cc = e & 7;           // kr octet: kr = cc*8
            const int k  = cc >> 1;
            const int r0 = (cc & 1) * 8;
            const float* sp = uw + (size_t)k * 16384 + (size_t)(oc * 256 + o) * 16 + r0;
            const float4 s0 = *reinterpret_cast<const float4*>(sp);
            const float4 s1 = *reinterpret_cast<const float4*>(sp + 4);
            *reinterpret_cast<bf16x8*>(&bs[o * 72 + cc * 8]) = cvt8(s0, s1);
        }
        __syncthreads();

#pragma unroll
        for (int ntl = 0; ntl < 8; ++ntl) {
            const int nt = kh * 8 + ntl;    // n-tile within this 256-col chunk
            const bf16x8 b0 = *reinterpret_cast<const bf16x8*>(&bs[(nt * 16 + fr) * 72 + kg]);
            const bf16x8 b1 = *reinterpret_cast<const bf16x8*>(&bs[(nt * 16 + fr) * 72 + 32 + kg]);
            f32x4 c2 = (f32x4){0.f, 0.f, 0.f, 0.f};
            c2 = __builtin_amdgcn_mfma_f32_16x16x32_bf16(pa0, b0, c2, 0, 0, 0);
            c2 = __builtin_amdgcn_mfma_f32_16x16x32_bf16(pa1, b1, c2, 0, 0, 0);
#pragma unroll
            for (int j = 0; j < 4; ++j)
                op[(size_t)j * O + oc * 256 + nt * 16 + fr] = c2[j];
        }
        __syncthreads();   // bs reads done before next oc stage
    }
}

} // namespace

extern "C" void kernel_launch(void* const* d_in, const int* in_sizes, int n_in,
                              void* d_out, int out_size, void* d_ws, size_t ws_size,
                              hipStream_t stream) {
    const float* hs    = (const float*)d_in[0];  // [4,4096,1024]
    const float* alpha = (const float*)d_in[1];  // [4,4]
    const float* dw    = (const float*)d_in[2];  // [4,16,1024]
    const float* uw    = (const float*)d_in[3];  // [4,1024,16]
    float* outp = (float*)d_out;

    hipLaunchKernelGGL(lora_mfma_k, dim3(512), dim3(256), 0, stream,
                       hs, alpha, dw, uw, outp);
}

// Round 7
// 32.600 us; speedup vs baseline: 1.5661x; 1.5661x over previous
//
#include <hip/hip_runtime.h>

namespace {

typedef short  bf16x8 __attribute__((ext_vector_type(8)));
typedef float  f32x4  __attribute__((ext_vector_type(4)));

constexpr int D = 1024;   // in_features
constexpr int O = 1024;   // out_features

// fp32 -> bf16 bits, round-to-nearest-even
__device__ __forceinline__ short f2bf(float f) {
    unsigned u = __builtin_bit_cast(unsigned, f);
    u += 0x7fffu + ((u >> 16) & 1u);
    return (short)(u >> 16);
}

__device__ __forceinline__ bf16x8 cvt8(const float4 a, const float4 b) {
    bf16x8 v;
    v[0] = f2bf(a.x); v[1] = f2bf(a.y); v[2] = f2bf(a.z); v[3] = f2bf(a.w);
    v[4] = f2bf(b.x); v[5] = f2bf(b.y); v[6] = f2bf(b.z); v[7] = f2bf(b.w);
    return v;
}

struct StageRegs { float4 a[4]; float4 b[4]; };

// ---- staging helpers (512 threads cooperate; full unroll => static reg idx) ----
__device__ __forceinline__ void issue_dw(const float* __restrict__ dw, int c, int t,
                                         StageRegs& r) {
#pragma unroll
    for (int i = 0; i < 4; ++i) {
        const int e = i * 512 + t, kr = e >> 5, cc = e & 31;
        const float* sp = dw + (size_t)kr * D + c * 256 + cc * 8;
        r.a[i] = *reinterpret_cast<const float4*>(sp);
        r.b[i] = *reinterpret_cast<const float4*>(sp + 4);
    }
}
__device__ __forceinline__ void write_p1(short* buf, int t, const StageRegs& r) {
#pragma unroll
    for (int i = 0; i < 4; ++i) {
        const int e = i * 512 + t, kr = e >> 5, cc = e & 31;
        *reinterpret_cast<bf16x8*>(&buf[kr * 264 + cc * 8]) = cvt8(r.a[i], r.b[i]);
    }
}
__device__ __forceinline__ void issue_uw(const float* __restrict__ uw, int oc, int t,
                                         StageRegs& r) {
#pragma unroll
    for (int i = 0; i < 4; ++i) {
        const int e = i * 512 + t, o = e >> 3, cc = e & 7;
        const int k = cc >> 1, r0 = (cc & 1) * 8;
        const float* sp = uw + (size_t)k * 16384 + (size_t)(oc * 256 + o) * 16 + r0;
        r.a[i] = *reinterpret_cast<const float4*>(sp);
        r.b[i] = *reinterpret_cast<const float4*>(sp + 4);
    }
}
__device__ __forceinline__ void write_p2(short* buf, int t, const StageRegs& r) {
#pragma unroll
    for (int i = 0; i < 4; ++i) {
        const int e = i * 512 + t, o = e >> 3, cc = e & 7;
        *reinterpret_cast<bf16x8*>(&buf[o * 72 + cc * 8]) = cvt8(r.a[i], r.b[i]);
    }
}

__device__ __forceinline__ void compute_p1(const short* __restrict__ buf,
                                           const float* __restrict__ ap,
                                           int fr, int kh, int kg, f32x4* acc) {
#pragma unroll
    for (int ks = 0; ks < 4; ++ks) {
        const float4 a0 = *reinterpret_cast<const float4*>(ap + ks * 32);
        const float4 a1 = *reinterpret_cast<const float4*>(ap + ks * 32 + 4);
        const bf16x8 av = cvt8(a0, a1);
#pragma unroll
        for (int nt = 0; nt < 4; ++nt) {
            const bf16x8 bv = *reinterpret_cast<const bf16x8*>(
                &buf[(nt * 16 + fr) * 264 + kh * 128 + ks * 32 + kg]);
            acc[nt] = __builtin_amdgcn_mfma_f32_16x16x32_bf16(av, bv, acc[nt], 0, 0, 0);
        }
    }
}

__device__ __forceinline__ void compute_p2(const short* __restrict__ buf,
                                           const bf16x8 pa0, const bf16x8 pa1,
                                           float* __restrict__ op,
                                           int oc, int fr, int kg, int kh) {
#pragma unroll
    for (int ntl = 0; ntl < 8; ++ntl) {
        const int nt = kh * 8 + ntl;
        const bf16x8 b0 = *reinterpret_cast<const bf16x8*>(&buf[(nt * 16 + fr) * 72 + kg]);
        const bf16x8 b1 = *reinterpret_cast<const bf16x8*>(&buf[(nt * 16 + fr) * 72 + 32 + kg]);
        f32x4 c2 = (f32x4){0.f, 0.f, 0.f, 0.f};
        c2 = __builtin_amdgcn_mfma_f32_16x16x32_bf16(pa0, b0, c2, 0, 0, 0);
        c2 = __builtin_amdgcn_mfma_f32_16x16x32_bf16(pa1, b1, c2, 0, 0, 0);
#pragma unroll
        for (int j = 0; j < 4; ++j)
            op[(size_t)j * O + oc * 256 + nt * 16 + fr] = c2[j];
    }
}

// Fused LoRA. 256 blocks x 512 threads (8 waves, 1 block/CU, 64 rows/block,
// weights staged once per block). Double-buffered staging: issue loads for
// chunk c+1, compute chunk c, cvt+write c+1, ONE barrier per chunk.
// Wave w: rt = w>>1 (16-row tile), kh = w&1 (K-half / N-half split).
__global__ void __launch_bounds__(512) lora_mfma_k(
        const float* __restrict__ hs,     // [16384][1024] f32
        const float* __restrict__ alpha,  // [4][4]
        const float* __restrict__ dw,     // [64][1024] f32  (k*16+r major)
        const float* __restrict__ uw,     // [4][1024][16] f32
        float* __restrict__ out) {        // [16384][1024] f32
    __shared__ __align__(16) short bs[2][18432];     // 73728 B (p1: [64][264], p2: [256][72])
    __shared__ __align__(16) short lowb[4][16][72];  // 9216 B
    __shared__ float pacc[4][16][64];                // 16384 B

    const int t    = threadIdx.x;
    const int w    = t >> 6;
    const int lane = t & 63;
    const int rt   = w >> 1;            // row-tile 0..3
    const int kh   = w & 1;             // K-half / N-half
    const int fr   = lane & 15;
    const int kgi  = lane >> 4;         // 0..3
    const int kg   = kgi * 8;
    const int rowblk = blockIdx.x * 64;
    const int b      = rowblk >> 12;    // batch (64-row blocks never straddle)
    const int myrow  = rowblk + rt * 16 + fr;
    const float* apb = hs + (size_t)myrow * D + kh * 128 + kg;

    StageRegs rg;
    f32x4 acc[4];
#pragma unroll
    for (int nt = 0; nt < 4; ++nt) acc[nt] = (f32x4){0.f, 0.f, 0.f, 0.f};

    // ---------------- phase 1: low = hs @ dw^T ----------------
    // prologue: stage dw chunk 0 -> bs[0]
    issue_dw(dw, 0, t, rg);
    write_p1(&bs[0][0], t, rg);
    __syncthreads();

#pragma unroll
    for (int c = 0; c < 3; ++c) {
        issue_dw(dw, c + 1, t, rg);                 // overlap with compute
        compute_p1(&bs[c & 1][0], apb + c * 256, fr, kh, kg, acc);
        write_p1(&bs[(c + 1) & 1][0], t, rg);
        __syncthreads();
    }
    // c = 3: prefetch phase-2 chunk 0 (uw) while computing last dw chunk
    issue_uw(uw, 0, t, rg);
    compute_p1(&bs[1][0], apb + 3 * 256, fr, kh, kg, acc);
    write_p2(&bs[0][0], t, rg);
    __syncthreads();

    // combine split-K partials; scale by alpha*4; bf16 low tile
    if (kh) {
#pragma unroll
        for (int nt = 0; nt < 4; ++nt)
#pragma unroll
            for (int j = 0; j < 4; ++j)
                pacc[rt][nt * 4 + j][lane] = acc[nt][j];
    }
    __syncthreads();
    if (!kh) {
#pragma unroll
        for (int nt = 0; nt < 4; ++nt) {
            const float sc = alpha[b * 4 + nt] * 4.0f;   // NETWORK_ALPHA/RANK = 4
#pragma unroll
            for (int j = 0; j < 4; ++j) {
                const float v = (acc[nt][j] + pacc[rt][nt * 4 + j][lane]) * sc;
                lowb[rt][kgi * 4 + j][nt * 16 + fr] = f2bf(v);
            }
        }
    }
    __syncthreads();

    // ---------------- phase 2: out = low @ up^T ----------------
    const bf16x8 pa0 = *reinterpret_cast<const bf16x8*>(&lowb[rt][fr][kg]);
    const bf16x8 pa1 = *reinterpret_cast<const bf16x8*>(&lowb[rt][fr][32 + kg]);
    float* op = out + (size_t)(rowblk + rt * 16 + kgi * 4) * O;

#pragma unroll
    for (int oc = 0; oc < 3; ++oc) {
        issue_uw(uw, oc + 1, t, rg);                // overlap with compute
        compute_p2(&bs[oc & 1][0], pa0, pa1, op, oc, fr, kg, kh);
        write_p2(&bs[(oc + 1) & 1][0], t, rg);
        __syncthreads();
    }
    compute_p2(&bs[1][0], pa0, pa1, op, 3, fr, kg, kh);
}

} // namespace

extern "C" void kernel_launch(void* const* d_in, const int* in_sizes, int n_in,
                              void* d_out, int out_size, void* d_ws, size_t ws_size,
                              hipStream_t stream) {
    const float* hs    = (const float*)d_in[0];  // [4,4096,1024]
    const float* alpha = (const float*)d_in[1];  // [4,4]
    const float* dw    = (const float*)d_in[2];  // [4,16,1024]
    const float* uw    = (const float*)d_in[3];  // [4,1024,16]
    float* outp = (float*)d_out;

    hipLaunchKernelGGL(lora_mfma_k, dim3(256), dim3(512), 0, stream,
                       hs, alpha, dw, uw, outp);
}